// Round 1
// baseline (1510.105 us; speedup 1.0000x reference)
//
#include <hip/hip_runtime.h>
#include <cstdint>
#include <cstddef>

typedef __bf16 bf16;
typedef __bf16 bf16x8 __attribute__((ext_vector_type(8)));
typedef float f32x4 __attribute__((ext_vector_type(4)));

#define BATCHN 128
#define HWN    225
#define PPLANE 28800      // BATCHN*HWN
#define M4     115200     // 4*PPLANE
#define EPI_SWISH     0
#define EPI_SWISH_ADD 1
#define EPI_TANH      2

__device__ __forceinline__ float swishf(float x){ return x / (1.f + __expf(-x)); }

__device__ __forceinline__ void diroff(int d, int o, int& dh, int& dw){
  if (d == 0)      { dh = 0;  dw = o; }
  else if (d == 1) { dh = o;  dw = 0; }
  else if (d == 2) { dh = o;  dw = o; }
  else             { dh = -o; dw = o; }
}

// ---------------- weight conversion fp32 -> bf16 ----------------
// W1L[j][oc][t*256+ic] <- rb_w[j][t][oc][ic]; rest are straight casts.
__global__ void k_wconv(const float* __restrict__ rbw, const float* __restrict__ rbw2,
                        const float* __restrict__ trw1, const float* __restrict__ trw2,
                        const float* __restrict__ fcw,
                        bf16* __restrict__ W1L, bf16* __restrict__ W2,
                        bf16* __restrict__ TW1, bf16* __restrict__ TW2,
                        bf16* __restrict__ FCW)
{
  int e = blockIdx.x * 256 + threadIdx.x;   // < 1,736,704 exactly
  if (e < 786432) {
    int j = e / 196608; int r = e - j * 196608;
    int oc = r / 768;   int k = r - oc * 768;
    int t = k >> 8;     int ic = k & 255;
    W1L[e] = (bf16)rbw[(((size_t)(j*3 + t) * 256 + oc) * 256) + ic];
    return;
  }
  int e2 = e - 786432;
  if (e2 < 262144) { W2[e2] = (bf16)rbw2[e2]; return; }
  int e3 = e2 - 262144;
  if (e3 < 327680) { TW1[e3] = (bf16)trw1[e3]; return; }
  int e4 = e3 - 327680;
  if (e4 < 327680) { TW2[e4] = (bf16)trw2[e4]; return; }
  int e5 = e4 - 327680;
  if (e5 < 32768)  { FCW[e5] = (bf16)fcw[e5]; }
}

// ---------------- first layer: y[d] = swish(line_conv3(x)) ----------------
__global__ void k_first(const float* __restrict__ x, const float* __restrict__ fw,
                        const float* __restrict__ fb, float* __restrict__ Y)
{
  int idx = blockIdx.x * 256 + threadIdx.x;   // M4*256 threads
  int c = idx & 255;
  int m = idx >> 8;
  int d = m / PPLANE;
  int r = m - d * PPLANE;
  int b = r / HWN;
  int hw = r - b * HWN;
  int h = hw / 15, w = hw - (hw / 15) * 15;
  float acc = fb[c];
  #pragma unroll
  for (int t = 0; t < 3; ++t) {
    int dh, dw; diroff(d, t - 1, dh, dw);
    int h2 = h + dh, w2 = w + dw;
    if ((unsigned)h2 < 15u && (unsigned)w2 < 15u) {
      int p2 = h2 * 15 + w2;
      acc += fw[(t*256 + c)*2 + 0] * x[(b*2 + 0)*HWN + p2]
           + fw[(t*256 + c)*2 + 1] * x[(b*2 + 1)*HWN + p2];
    }
  }
  Y[(size_t)m * 256 + c] = swishf(acc);
}

// ---------------- main GEMM: out[m][n] = epi(A[m][:]·Wt[n][:] + bias[n]) ----------------
// A: fp32 (AF32) or bf16; KTOT==768 => line-conv gather from Y (fp32) with OOB->zero page.
template<int EPI, int KTOT, bool AF32>
__launch_bounds__(256, 2)
__global__ void k_gemm(const void* __restrict__ Abase, const bf16* __restrict__ Wt,
                       const float* __restrict__ biasp, void* __restrict__ outp,
                       const float* __restrict__ Yres, const float* __restrict__ zpf)
{
  constexpr bool LINE = (KTOT == 768);
  static_assert(!LINE || AF32, "line gather reads fp32 Y");
  __shared__ __align__(16) bf16 As[128*72];
  __shared__ __align__(16) bf16 Bs[128*72];
  const int tid = threadIdx.x;
  const int lane = tid & 63;
  const int m0 = blockIdx.x * 128;
  const int n0 = blockIdx.y * 128;
  const int wv = tid >> 6;
  const int wm = wv >> 1, wn = wv & 1;

  int srow[4], skseg[4];
  const bf16* bptr[4];
  const float* arowf[4];
  const bf16* arowb[4];
  int pbase[4], ph[4], pw[4];
  int dplane = 0;
  if (LINE) dplane = m0 / PPLANE;

  #pragma unroll
  for (int i = 0; i < 4; ++i) {
    int u = i * 256 + tid;
    srow[i]  = u >> 3;
    skseg[i] = u & 7;
    bptr[i] = Wt + (size_t)(n0 + srow[i]) * KTOT + skseg[i]*8;
    int m = m0 + srow[i];
    if (LINE) {
      int r = m - dplane * PPLANE;
      int b = r / HWN;
      int hw = r - b * HWN;
      pbase[i] = (dplane * BATCHN + b) * HWN;
      ph[i] = hw / 15;
      pw[i] = hw - (hw / 15) * 15;
    } else if (AF32) {
      arowf[i] = (const float*)Abase + (size_t)m * 256 + skseg[i]*8;
    } else {
      arowb[i] = (const bf16*)Abase + (size_t)m * 256 + skseg[i]*8;
    }
  }

  f32x4 acc[4][4];
  #pragma unroll
  for (int a = 0; a < 4; ++a)
    #pragma unroll
    for (int b = 0; b < 4; ++b) { f32x4 z = {0.f,0.f,0.f,0.f}; acc[a][b] = z; }

  bf16x8 av[4], bv[4];

  auto loadAB = [&](int kt) {
    #pragma unroll
    for (int i = 0; i < 4; ++i) {
      if (AF32) {
        const float* ap;
        if (LINE) {
          int t = kt >> 2;
          int dh, dw; diroff(dplane, t - 1, dh, dw);
          int h2 = ph[i] + dh, w2 = pw[i] + dw;
          if ((unsigned)h2 < 15u && (unsigned)w2 < 15u)
            ap = (const float*)Abase + (size_t)(pbase[i] + h2*15 + w2) * 256 + (kt & 3)*64 + skseg[i]*8;
          else
            ap = zpf + skseg[i]*8;
        } else {
          ap = arowf[i] + kt * 64;
        }
        float4 f0 = *(const float4*)ap;
        float4 f1 = *(const float4*)(ap + 4);
        bf16x8 cv;
        cv[0] = (bf16)f0.x; cv[1] = (bf16)f0.y; cv[2] = (bf16)f0.z; cv[3] = (bf16)f0.w;
        cv[4] = (bf16)f1.x; cv[5] = (bf16)f1.y; cv[6] = (bf16)f1.z; cv[7] = (bf16)f1.w;
        av[i] = cv;
      } else {
        av[i] = *(const bf16x8*)(arowb[i] + kt * 64);
      }
      bv[i] = *(const bf16x8*)(bptr[i] + kt * 64);
    }
  };

  loadAB(0);
  constexpr int KT = KTOT / 64;
  for (int kt = 0; kt < KT; ++kt) {
    __syncthreads();
    #pragma unroll
    for (int i = 0; i < 4; ++i) {
      int off = srow[i]*72 + skseg[i]*8;
      *(bf16x8*)&As[off] = av[i];
      *(bf16x8*)&Bs[off] = bv[i];
    }
    __syncthreads();
    if (kt + 1 < KT) loadAB(kt + 1);
    #pragma unroll
    for (int ks = 0; ks < 2; ++ks) {
      bf16x8 af[4], bfr[4];
      #pragma unroll
      for (int mt = 0; mt < 4; ++mt)
        af[mt] = *(const bf16x8*)&As[(wm*64 + mt*16 + (lane & 15))*72 + ks*32 + (lane >> 4)*8];
      #pragma unroll
      for (int nt = 0; nt < 4; ++nt)
        bfr[nt] = *(const bf16x8*)&Bs[(wn*64 + nt*16 + (lane & 15))*72 + ks*32 + (lane >> 4)*8];
      #pragma unroll
      for (int mt = 0; mt < 4; ++mt)
        #pragma unroll
        for (int nt = 0; nt < 4; ++nt)
          acc[mt][nt] = __builtin_amdgcn_mfma_f32_16x16x32_bf16(af[mt], bfr[nt], acc[mt][nt], 0, 0, 0);
    }
  }

  #pragma unroll
  for (int mt = 0; mt < 4; ++mt) {
    #pragma unroll
    for (int nt = 0; nt < 4; ++nt) {
      int col = n0 + wn*64 + nt*16 + (lane & 15);
      int rbase = m0 + wm*64 + mt*16 + ((lane >> 4) << 2);
      float bb = biasp[col];
      #pragma unroll
      for (int r = 0; r < 4; ++r) {
        float v = acc[mt][nt][r] + bb;
        size_t mm = (size_t)(rbase + r);
        if (EPI == EPI_SWISH) {
          ((bf16*)outp)[mm*256 + col] = (bf16)swishf(v);
        } else if (EPI == EPI_SWISH_ADD) {
          ((float*)outp)[mm*256 + col] = swishf(v) + Yres[mm*256 + col];
        } else {
          ((float*)outp)[mm*128 + col] = 30.f * tanhf(v * (1.f/30.f));
        }
      }
    }
  }
}

// ---------------- h1 = prelu(mean_d g1, g1lr_s, bound .999) ----------------
// mapf layout [d][b][hw][c128]; h1 layout [b][c][hw] (planar)
__global__ void k_h1(const float* __restrict__ mapf, const float* __restrict__ g1s,
                     float* __restrict__ h1)
{
  __shared__ float accs[225*65];
  int b = blockIdx.x, tid = threadIdx.x;
  for (int d = 0; d < 4; ++d) {
    for (int e = tid; e < 225*64; e += 256) {
      int hw = e >> 6, c = e & 63;
      float v = mapf[((size_t)(d*BATCHN + b)*225 + hw)*128 + c];
      if (d == 0) accs[hw*65 + c] = v; else accs[hw*65 + c] += v;
    }
  }
  __syncthreads();
  for (int e = tid; e < 225*64; e += 256) {
    int c = e / 225, hw = e - c*225;
    float s = tanhf(g1s[c] * (1.f/0.999f)) * 0.999f;
    float v = accs[hw*65 + c] * 0.25f;
    h1[((size_t)b*64 + c)*225 + hw] = fmaxf(v, s*v);
  }
}

// ---------------- h1c(avg sym) -> h2 -> h3 -> trunk0 ----------------
__global__ void k_h2(const float* __restrict__ h1, const float* __restrict__ mapf,
                     const float* __restrict__ h1w, const float* __restrict__ h1b,
                     const float* __restrict__ s1p, const float* __restrict__ s2p,
                     const float* __restrict__ s3p, const float* __restrict__ b3p,
                     float* __restrict__ tr0)
{
  int bc = blockIdx.x; int b = bc >> 6; int c = bc & 63;
  __shared__ float pl[225];
  int tid = threadIdx.x;
  if (tid < 225) pl[tid] = h1[((size_t)b*64 + c)*225 + tid];
  __syncthreads();
  if (tid >= 225) return;
  int h = tid / 15, w = tid - (tid/15)*15;
  float wk[11];
  #pragma unroll
  for (int i = 0; i < 11; ++i) wk[i] = h1w[i*64 + c];
  float bias = h1b[c];
  float sl1 = tanhf(s1p[c] * (1.f/0.999f)) * 0.999f;
  float sl2 = tanhf(s2p[c] * (1.f/0.999f)) * 0.999f;
  float tsum = 0.f;
  for (int d = 0; d < 4; ++d) {
    float hc = bias;
    #pragma unroll
    for (int i = 0; i < 11; ++i) {
      int dh, dw; diroff(d, i - 5, dh, dw);
      int hp = h + dh, wp = w + dw;
      float vp = ((unsigned)hp < 15u && (unsigned)wp < 15u) ? pl[hp*15 + wp] : 0.f;
      int hm = h - dh, wm = w - dw;
      float vm = ((unsigned)hm < 15u && (unsigned)wm < 15u) ? pl[hm*15 + wm] : 0.f;
      hc += 0.5f * wk[i] * (vp + vm);
    }
    float t = fmaxf(hc, sl1*hc);
    t += mapf[((size_t)(d*BATCHN + b)*225 + tid)*128 + 64 + c];
    t = fmaxf(t, sl2*t);
    tsum += t;
  }
  float h3v = tsum * 0.25f + b3p[c];
  float sl3 = tanhf(s3p[c] * (1.f/0.999f)) * 0.999f;
  tr0[((size_t)b*64 + c)*225 + tid] = fmaxf(h3v, sl3*h3v);
}

// ---------------- shuffle -> grouped 1x1 (16x(4x4)) -> shuffle -> prelu ----------------
__global__ void k_head1(const float* __restrict__ tr0, const float* __restrict__ tc1w,
                        const float* __restrict__ tc1b, const float* __restrict__ tlr1,
                        float* __restrict__ t1o)
{
  __shared__ float st[64*228];
  int b = blockIdx.x, tid = threadIdx.x;
  for (int e = tid; e < 64*225; e += 256) {
    int c = e / 225, hw = e - c*225;
    st[c*228 + hw] = tr0[((size_t)b*64 + c)*225 + hw];
  }
  __syncthreads();
  float s2v[64];
  if (tid < 225) {
    #pragma unroll
    for (int g = 0; g < 16; ++g) {
      int gg = g >> 2, rr = g & 3;
      float x0 = st[(gg*16 + 0*4 + rr)*228 + tid];
      float x1 = st[(gg*16 + 1*4 + rr)*228 + tid];
      float x2 = st[(gg*16 + 2*4 + rr)*228 + tid];
      float x3 = st[(gg*16 + 3*4 + rr)*228 + tid];
      #pragma unroll
      for (int o = 0; o < 4; ++o) {
        s2v[g*4 + o] = tc1b[g*4 + o]
          + x0*tc1w[(g*4 + o)*4 + 0] + x1*tc1w[(g*4 + o)*4 + 1]
          + x2*tc1w[(g*4 + o)*4 + 2] + x3*tc1w[(g*4 + o)*4 + 3];
      }
    }
  }
  __syncthreads();
  if (tid < 225) {
    #pragma unroll
    for (int c = 0; c < 64; ++c) {
      int gg = c >> 4, q = c & 15, ii = q >> 2, jj = q & 3;
      float v = s2v[gg*16 + jj*4 + ii];
      float sl = tanhf(tlr1[c] * (1.f/0.999f)) * 0.999f;
      st[c*228 + tid] = fmaxf(v, sl*v);
    }
  }
  __syncthreads();
  for (int e = tid; e < 64*225; e += 256) {
    int c = e / 225, hw = e - c*225;
    t1o[((size_t)b*64 + c)*225 + hw] = st[c*228 + hw];
  }
}

// ---------------- sym3 depthwise conv + policy head + value pre-pool ----------------
__global__ void k_head2(const float* __restrict__ t1, const float* __restrict__ tc2w,
                        const float* __restrict__ t2ps, const float* __restrict__ t2pb,
                        const float* __restrict__ t2vs, const float* __restrict__ t2vb,
                        const float* __restrict__ polw,
                        float* __restrict__ pout, float* __restrict__ vpre)
{
  __shared__ float st[64*228];
  __shared__ float vbuf[64*228];
  __shared__ float psum[64*4];
  int b = blockIdx.x, tid = threadIdx.x;
  for (int e = tid; e < 64*225; e += 256) {
    int c = e / 225, hw = e - c*225;
    st[c*228 + hw] = t1[((size_t)b*64 + c)*225 + hw];
  }
  __syncthreads();
  if (tid < 225) {
    int h = tid / 15, w = tid - (tid/15)*15;
    float pacc = 0.f;
    for (int c = 0; c < 64; ++c) {
      const float* pc = &st[c*228];
      float ctr = pc[tid];
      float up = (h > 0)  ? pc[tid - 15] : 0.f;
      float dn = (h < 14) ? pc[tid + 15] : 0.f;
      float lf = (w > 0)  ? pc[tid - 1]  : 0.f;
      float rt = (w < 14) ? pc[tid + 1]  : 0.f;
      float ul = (h > 0  && w > 0)  ? pc[tid - 16] : 0.f;
      float ur = (h > 0  && w < 14) ? pc[tid - 14] : 0.f;
      float dl = (h < 14 && w > 0)  ? pc[tid + 14] : 0.f;
      float dr = (h < 14 && w < 14) ? pc[tid + 16] : 0.f;
      float s3 = tc2w[c]*ctr + tc2w[64 + c]*(up + dn + lf + rt)
               + tc2w[128 + c]*(ul + ur + dl + dr);
      float yp = s3 + t2pb[c];
      float sp = tanhf(t2ps[c] * (1.f/0.999f)) * 0.999f;
      pacc += fmaxf(yp, sp*yp) * polw[c];
      float yv = s3 + t2vb[c];
      float sv = tanhf(t2vs[c] * (1.f/0.999f)) * 0.999f;
      vbuf[c*228 + tid] = fmaxf(yv, sv*yv);
    }
    pout[(size_t)b*225 + tid] = pacc;
  }
  __syncthreads();
  {
    int c = tid & 63, q = tid >> 6;
    int h0 = q * 57; int h1e = (h0 + 57 < 225) ? h0 + 57 : 225;
    float s = 0.f;
    for (int hw = h0; hw < h1e; ++hw) s += vbuf[c*228 + hw];
    psum[c*4 + q] = s;
  }
  __syncthreads();
  if (tid < 64) {
    float s = (psum[tid*4] + psum[tid*4+1] + psum[tid*4+2] + psum[tid*4+3]) * (1.f/225.f);
    vpre[(size_t)b*64 + tid] = s;
  }
}

// ---------------- value MLP ----------------
__global__ void k_mlp(const float* __restrict__ vpre, const float* __restrict__ vls,
                      const float* __restrict__ vlb,
                      const float* __restrict__ w1, const float* __restrict__ b1,
                      const float* __restrict__ w2, const float* __restrict__ b2,
                      const float* __restrict__ w3, const float* __restrict__ b3,
                      const float* __restrict__ wf, const float* __restrict__ bfv,
                      float* __restrict__ vout)
{
  __shared__ float va[64], vb2[64];
  int b = blockIdx.x, t = threadIdx.x;   // 64 threads
  float x = vpre[(size_t)b*64 + t];
  float s = tanhf(vls[t] * 0.1f) * 10.f;
  float y = x + vlb[t];
  va[t] = fmaxf(y, s*y);
  __syncthreads();
  float acc = b1[t];
  for (int i = 0; i < 64; ++i) acc += w1[t*64 + i] * va[i];
  vb2[t] = fmaxf(acc, 0.f);
  __syncthreads();
  acc = b2[t];
  for (int i = 0; i < 64; ++i) acc += w2[t*64 + i] * vb2[i];
  va[t] = fmaxf(acc, 0.f);
  __syncthreads();
  acc = b3[t];
  for (int i = 0; i < 64; ++i) acc += w3[t*64 + i] * va[i];
  vb2[t] = fmaxf(acc, 0.f);
  __syncthreads();
  if (t < 3) {
    float o = bfv[t];
    for (int i = 0; i < 64; ++i) o += wf[t*64 + i] * vb2[i];
    vout[(size_t)b*3 + t] = o;
  }
}

extern "C" void kernel_launch(void* const* d_in, const int* in_sizes, int n_in,
                              void* d_out, int out_size, void* d_ws, size_t ws_size,
                              hipStream_t stream)
{
  (void)in_sizes; (void)n_in; (void)out_size; (void)ws_size;
  const float* x     = (const float*)d_in[0];
  const float* fw    = (const float*)d_in[1];
  const float* fb    = (const float*)d_in[2];
  const float* rb_w  = (const float*)d_in[3];
  const float* rb_b  = (const float*)d_in[4];
  const float* rb_w2 = (const float*)d_in[5];
  const float* rb_b2 = (const float*)d_in[6];
  const float* tr_w1 = (const float*)d_in[7];
  const float* tr_b1 = (const float*)d_in[8];
  const float* tr_w2 = (const float*)d_in[9];
  const float* tr_b2 = (const float*)d_in[10];
  const float* fc_w  = (const float*)d_in[11];
  const float* fc_b  = (const float*)d_in[12];
  const float* g1lr  = (const float*)d_in[13];
  const float* h1w   = (const float*)d_in[14];
  const float* h1b   = (const float*)d_in[15];
  const float* h1lr1 = (const float*)d_in[16];
  const float* h1lr2 = (const float*)d_in[17];
  const float* h3lr  = (const float*)d_in[18];
  const float* h3lb  = (const float*)d_in[19];
  const float* tc1w  = (const float*)d_in[20];
  const float* tc1b  = (const float*)d_in[21];
  const float* tlr1  = (const float*)d_in[22];
  const float* tc2w  = (const float*)d_in[23];
  const float* t2ps  = (const float*)d_in[24];
  const float* t2pb  = (const float*)d_in[25];
  const float* t2vs  = (const float*)d_in[26];
  const float* t2vb  = (const float*)d_in[27];
  const float* polw  = (const float*)d_in[28];
  const float* vls   = (const float*)d_in[29];
  const float* vlb   = (const float*)d_in[30];
  const float* v1w   = (const float*)d_in[31];
  const float* v1b   = (const float*)d_in[32];
  const float* v2w   = (const float*)d_in[33];
  const float* v2b   = (const float*)d_in[34];
  const float* v3w   = (const float*)d_in[35];
  const float* v3b   = (const float*)d_in[36];
  const float* vfw   = (const float*)d_in[37];
  const float* vfb   = (const float*)d_in[38];

  char* ws = (char*)d_ws;
  size_t off = 0;
  auto alloc = [&](size_t bytes) -> void* {
    void* p = ws + off;
    off += (bytes + 255) & ~(size_t)255;
    return p;
  };
  float* Y    = (float*)alloc((size_t)M4*256*4);   // fp32 residual master
  bf16*  T    = (bf16*) alloc((size_t)M4*256*2);   // bf16 intermediate
  float* MAPF = (float*)alloc((size_t)M4*128*4);
  float* H1   = (float*)alloc((size_t)BATCHN*64*225*4);
  float* TR0  = (float*)alloc((size_t)BATCHN*64*225*4);
  float* T1B  = (float*)alloc((size_t)BATCHN*64*225*4);
  float* VPRE = (float*)alloc((size_t)BATCHN*64*4);
  bf16* W1L = (bf16*)alloc((size_t)4*256*768*2);
  bf16* W2  = (bf16*)alloc((size_t)4*256*256*2);
  bf16* TW1 = (bf16*)alloc((size_t)5*256*256*2);
  bf16* TW2 = (bf16*)alloc((size_t)5*256*256*2);
  bf16* FCW = (bf16*)alloc((size_t)128*256*2);
  float* ZP = (float*)alloc(4096);

  hipMemsetAsync(ZP, 0, 4096, stream);
  k_wconv<<<6784, 256, 0, stream>>>(rb_w, rb_w2, tr_w1, tr_w2, fc_w, W1L, W2, TW1, TW2, FCW);
  k_first<<<115200, 256, 0, stream>>>(x, fw, fb, Y);

  dim3 g2(900, 2), g1(900, 1);
  for (int j = 0; j < 4; ++j) {
    k_gemm<EPI_SWISH, 768, true><<<g2, 256, 0, stream>>>(
        Y, W1L + (size_t)j*256*768, rb_b + j*256, T, nullptr, ZP);
    k_gemm<EPI_SWISH_ADD, 256, false><<<g2, 256, 0, stream>>>(
        T, W2 + (size_t)j*65536, rb_b2 + j*256, Y, Y, ZP);
  }
  for (int j = 0; j < 5; ++j) {
    k_gemm<EPI_SWISH, 256, true><<<g2, 256, 0, stream>>>(
        Y, TW1 + (size_t)j*65536, tr_b1 + j*256, T, nullptr, ZP);
    k_gemm<EPI_SWISH_ADD, 256, false><<<g2, 256, 0, stream>>>(
        T, TW2 + (size_t)j*65536, tr_b2 + j*256, Y, Y, ZP);
  }
  k_gemm<EPI_TANH, 256, true><<<g1, 256, 0, stream>>>(
      Y, FCW, fc_b, MAPF, nullptr, ZP);

  k_h1<<<128, 256, 0, stream>>>(MAPF, g1lr, H1);
  k_h2<<<8192, 256, 0, stream>>>(H1, MAPF, h1w, h1b, h1lr1, h1lr2, h3lr, h3lb, TR0);
  k_head1<<<128, 256, 0, stream>>>(TR0, tc1w, tc1b, tlr1, T1B);
  float* dout = (float*)d_out;
  k_head2<<<128, 256, 0, stream>>>(T1B, tc2w, t2ps, t2pb, t2vs, t2vb, polw, dout + 384, VPRE);
  k_mlp<<<128, 64, 0, stream>>>(VPRE, vls, vlb, v1w, v1b, v2w, v2b, v3w, v3b, vfw, vfb, dout);
}